// Round 20
// baseline (66.952 us; speedup 1.0000x reference)
//
#include <hip/hip_runtime.h>
#include <hip/hip_bf16.h>

#define T_DIM 800
#define B_DIM 32
#define V_DIM 1024
#define S_DIM 100
#define L2E  1.4426950408889634f
#define LN2  0.6931471805599453f

#define NB1  1600                /* K1 blocks: 16 rows each */
#define EOFF 4096                /* E starts at ws + EOFF floats (16 KB) */
#define EROW 128                 /* padded E row: 104 used slots (512 B) */
#define BROWS 801                /* per-batch row stride (row 800 = overrun pad) */
#define EBOFF (EOFF + 32 * BROWS * EROW)   /* EB[32][896] blank-emission sidecar */
#define EBSTR 896

// ws layout (32-bit slots):
// [0]                  : uint counter (zeroed by ctc_prep block 0 each call)
// [1 .. 1+NB1)         : float partial sums (smoothing reduction)
// [1+NB1 .. 1+NB1+32)  : float per-batch nll
// [EOFF ..)            : E[32][801][128] emission matrix (13.1 MB)
// [EBOFF ..)           : EB[32][896] per-row blank emission (114 KB)

__device__ __forceinline__ float dpp_shr1_f(float x) {
    return __int_as_float(__builtin_amdgcn_update_dpp(
        0, __float_as_int(x), 0x138, 0xF, 0xF, false));
}
__device__ __forceinline__ int dpp_shr1_i(int x) {
    return __builtin_amdgcn_update_dpp(0, x, 0x138, 0xF, 0xF, false);
}
__device__ __forceinline__ float rl50(float x) {
    return __int_as_float(__builtin_amdgcn_readlane(__float_as_int(x), 50));
}
__device__ __forceinline__ void gl16(const float* g, float* lds_dst) {
    __builtin_amdgcn_global_load_lds(
        (const __attribute__((address_space(1))) unsigned int*)g,
        (__attribute__((address_space(3))) unsigned int*)lds_dst,
        16, 0, 0);
}
__device__ __forceinline__ void gl4(const float* g, float* lds_dst) {
    __builtin_amdgcn_global_load_lds(
        (const __attribute__((address_space(1))) unsigned int*)g,
        (__attribute__((address_space(3))) unsigned int*)lds_dst,
        4, 0, 0);
}

// ========== K1: smoothing-reduction + E build (+EB sidecar) ==========
extern "C" __global__ void __launch_bounds__(256)
ctc_prep(const float* __restrict__ lp,
         const int* __restrict__ tgt,
         float* __restrict__ ws)
{
    __shared__ float rb[4][V_DIM];      // 16 KB: per-wave single buffer
    __shared__ float red[4];
    float* E = ws + EOFF;
    float* EBp = ws + EBOFF;
    float* partials = ws + 1;
    const int bid = blockIdx.x;
    const int tid = threadIdx.x;
    const int w = tid >> 6, j = tid & 63;
    const int b  = bid / 50;            // 50 blocks per batch
    const int t0 = (bid - b * 50) * 16 + w * 4;
    const int* tg = tgt + b * S_DIM;

    if (bid == 0 && tid == 0) ((unsigned int*)ws)[0] = 0;   // zero rec counter

    int c1 = 0, c2 = 0;
    if (j <= 49) { int2 t2 = ((const int2*)tg)[j]; c1 = t2.x; c2 = t2.y; }

    const float* base = lp + ((size_t)t0 * B_DIM + b) * V_DIM;
    const size_t RSTRIDE = (size_t)B_DIM * V_DIM;

    const float4* s0 = (const float4*)base;
    float4 A = s0[j], Bv = s0[j + 64], C = s0[j + 128], D = s0[j + 192];

    float s = 0.0f;
    #pragma unroll
    for (int i = 0; i < 4; ++i) {
        float4 A2 = A, B2 = Bv, C2 = C, D2 = D;
        if (i < 3) {
            const float4* sn = (const float4*)(base + (size_t)(i + 1) * RSTRIDE);
            A2 = sn[j]; B2 = sn[j + 64]; C2 = sn[j + 128]; D2 = sn[j + 192];
        }
        s += ((A.x + A.y) + (A.z + A.w)) + ((Bv.x + Bv.y) + (Bv.z + Bv.w))
           + ((C.x + C.y) + (C.z + C.w)) + ((D.x + D.y) + (D.z + D.w));
        float* rw = rb[w];
        ((float4*)rw)[j] = A; ((float4*)rw)[j + 64] = Bv;
        ((float4*)rw)[j + 128] = C; ((float4*)rw)[j + 192] = D;
        float a, c;
        if (j <= 49)      { a = __builtin_amdgcn_exp2f(rw[c1] * L2E);
                            c = __builtin_amdgcn_exp2f(rw[c2] * L2E); }
        else if (j == 50) { float ebv = __builtin_amdgcn_exp2f(rw[0] * L2E);
                            a = ebv; c = ebv;
                            EBp[(size_t)b * EBSTR + t0 + i] = ebv; }
        else              { a = 0.0f; c = 0.0f; }
        ((float2*)(E + ((size_t)b * BROWS + t0 + i) * EROW))[j] = make_float2(a, c);
        A = A2; Bv = B2; C = C2; D = D2;
    }
    for (int off = 32; off; off >>= 1) s += __shfl_down(s, off, 64);
    if (j == 0) red[w] = s;
    __syncthreads();
    if (tid == 0) partials[bid] = (red[0] + red[1]) + (red[2] + red[3]);
}

// ========== K2: recursion — wave split + upfront SB loads, no in-loop readlane ==========
extern "C" __global__ void __launch_bounds__(128)
ctc_rec(const int* __restrict__ tgt,
        const int* __restrict__ ilen,
        const int* __restrict__ tlen,
        float* __restrict__ ws,
        float* __restrict__ out)
{
    __shared__ float bufA[32 * EROW];   // 16 KB
    __shared__ float bufB[32 * EROW];   // 16 KB
    __shared__ __align__(16) float ebA[64];
    __shared__ __align__(16) float ebB[64];
    unsigned int* cnt = (unsigned int*)ws;
    float* partials = ws + 1;
    float* nlls = ws + 1 + NB1;
    const int b = blockIdx.x;
    const int tid = threadIdx.x;
    const int wav = tid >> 6;
    const int l = tid & 63;
    const float* E = ws + EOFF + (size_t)b * BROWS * EROW;
    const float* EBb = ws + EBOFF + (size_t)b * EBSTR;
    const int* tg = tgt + b * S_DIM;
    const int len = ilen[b];
    const int tl  = tlen[b];
    const int steps = len - 1;          // t = 1..len-1 ; len in [400,800]
    const int nfull = steps >> 5;
    const int nst   = steps & 31;
    const int N     = nfull + (nst ? 1 : 0);

#define STAGE_P(BUFP, EBP, SB) do { \
    const int tb_ = 1 + 32 * (SB); \
    float* bp_ = (BUFP); \
    _Pragma("unroll") \
    for (int g_ = 0; g_ < 16; ++g_) { \
        gl16(E + (size_t)(tb_ + 2 * g_) * EROW + 4 * l, bp_ + g_ * 256); \
    } \
    gl4(EBb + tb_ + l, (EBP)); \
} while (0)

#define WAIT0 do { \
    asm volatile("s_waitcnt vmcnt(0)" ::: "memory"); \
    __builtin_amdgcn_sched_barrier(0); \
} while (0)

    if (wav == 1) {
        // ---------------- stager wave ----------------
        STAGE_P(bufA, ebA, 0); WAIT0;
        __builtin_amdgcn_s_barrier();                // bar#0: buf(0) ready
        #pragma unroll 1
        for (int k = 1; k < N; ++k) {
            if (k & 1) { STAGE_P(bufB, ebB, k); } else { STAGE_P(bufA, ebA, k); }
            WAIT0;
            __builtin_amdgcn_s_barrier();            // bar#k
        }
        return;                                       // exactly N barriers
    }

    // ---------------- consumer wave ----------------
    float cs1f = 0, cs3f = 0;
    if (l <= 49) {
        int v1 = tg[2 * l];
        int vp = (l >= 1) ? tg[2 * l - 1] : -1;
        cs1f = (v1 != vp) ? 1.0f : 0.0f;
        int v3 = tg[2 * l + 1];
        cs3f = (v3 != v1) ? 1.0f : 0.0f;
    }

    float p0 = 0, p1 = 0, p2 = 0, p3 = 0;
    float qv = 0, sff = 0, sfg = 0;
    int   el = 0, eLp = 0;
    {
        float2 q0 = ((const float2*)E)[l];
        float eb0 = rl50(q0.x);
        p0 = (l == 0) ? eb0  : 0.0f;
        p1 = (l == 0) ? q0.x : 0.0f;
    }

    // 8 groups x 4 float2 + 8 float4 eb — all named, loaded upfront per SB
    float2 g0r0, g0r1, g0r2, g0r3, g1r0, g1r1, g1r2, g1r3;
    float2 g2r0, g2r1, g2r2, g2r3, g3r0, g3r1, g3r2, g3r3;
    float2 g4r0, g4r1, g4r2, g4r3, g5r0, g5r1, g5r2, g5r3;
    float2 g6r0, g6r1, g6r2, g6r3, g7r0, g7r1, g7r2, g7r3;
    float4 eb40, eb41, eb42, eb43, eb44, eb45, eb46, eb47;

#define LOADG(BUF, EBB, G) do { \
    const float2* bp_ = (const float2*)(BUF); \
    g##G##r0 = bp_[(4 * G + 0) * 64 + l]; \
    g##G##r1 = bp_[(4 * G + 1) * 64 + l]; \
    g##G##r2 = bp_[(4 * G + 2) * 64 + l]; \
    g##G##r3 = bp_[(4 * G + 3) * 64 + l]; \
    eb4##G = ((const float4*)(EBB))[G]; \
} while (0)

#define LOADALL(BUF, EBB) do { \
    LOADG(BUF, EBB, 0); LOADG(BUF, EBB, 1); LOADG(BUF, EBB, 2); LOADG(BUF, EBB, 3); \
    LOADG(BUF, EBB, 4); LOADG(BUF, EBB, 5); LOADG(BUF, EBB, 6); LOADG(BUF, EBB, 7); \
} while (0)

#define BD do { \
    float mz_ = fmaxf(fmaxf(p0, p1), fmaxf(p2, p3)); \
    int dead_ = (mz_ == 0.0f) ? 1 : 0; \
    int er_ = (int)((__float_as_uint(mz_) >> 23) & 255u); \
    unsigned fld_ = dead_ ? 127u : (unsigned)(254 - er_); \
    float sc_ = __uint_as_float(fld_ << 23); \
    p0 *= sc_; p1 *= sc_; p2 *= sc_; p3 *= sc_; \
    el += dead_ ? 0 : (er_ - 127); \
    int e1s_ = dpp_shr1_i(el); \
    int elA_ = dead_ ? e1s_ : el; \
    int e2s_ = dpp_shr1_i(elA_); \
    int elB_ = dead_ ? e2s_ : el; \
    int e3s_ = dpp_shr1_i(elB_); \
    int d1_ = e3s_ - elB_; d1_ = d1_ < -120 ? -120 : (d1_ > 120 ? 120 : d1_); \
    int d2_ = eLp  - elB_; d2_ = d2_ < -120 ? -120 : (d2_ > 120 ? 120 : d2_); \
    sfg = (l == 0) ? 0.0f : __uint_as_float((unsigned)(d1_ + 127) << 23); \
    sff = (l == 0) ? 0.0f : __uint_as_float((unsigned)(d2_ + 127) << 23); \
    el = elB_; eLp = e3s_; \
} while (0)

#define ST(SF, Q, EBS) do { \
    float h3_ = qv * (SF); \
    float vown_ = fmaf(cs3f, p1, p2 + p3); \
    float n3_ = vown_ * (Q).y; \
    float n0_ = (p0 + h3_) * (EBS); \
    float n1_ = fmaf(cs1f, h3_, p0 + p1) * (Q).x; \
    float n2_ = (p1 + p2) * (EBS); \
    qv = dpp_shr1_f(n3_); \
    p0 = n0_; p1 = n1_; p2 = n2_; p3 = n3_; \
} while (0)

#define GRPX(G) do { \
    BD; \
    ST(sff, g##G##r0, eb4##G.x); \
    ST(sfg, g##G##r1, eb4##G.y); \
    ST(sfg, g##G##r2, eb4##G.z); \
    ST(sfg, g##G##r3, eb4##G.w); \
} while (0)

#define GRPTX(G, BASE) do { \
    if ((BASE) < nst) { \
        BD; \
        ST(sff, g##G##r0, eb4##G.x); \
        if ((BASE) + 1 < nst) ST(sfg, g##G##r1, eb4##G.y); \
        if ((BASE) + 2 < nst) ST(sfg, g##G##r2, eb4##G.z); \
        if ((BASE) + 3 < nst) ST(sfg, g##G##r3, eb4##G.w); \
    } \
} while (0)

#define CONS_FULL(BUF, EBB) do { \
    LOADALL(BUF, EBB); \
    GRPX(0); GRPX(1); GRPX(2); GRPX(3); \
    GRPX(4); GRPX(5); GRPX(6); GRPX(7); \
} while (0)

#define CONS_TAIL(BUF, EBB) do { \
    LOADALL(BUF, EBB); \
    GRPTX(0, 0);  GRPTX(1, 4);  GRPTX(2, 8);  GRPTX(3, 12); \
    GRPTX(4, 16); GRPTX(5, 20); GRPTX(6, 24); GRPTX(7, 28); \
} while (0)

    __builtin_amdgcn_s_barrier();                    // bar#0: buf(0) ready
    #pragma unroll 1
    for (int k = 0; k + 1 < N; ++k) {
        if (k & 1) { CONS_FULL(bufB, ebB); } else { CONS_FULL(bufA, ebA); }
        __builtin_amdgcn_s_barrier();                // bar#k+1
    }
    {
        const int kk = (N - 1) & 1;
        if (nst) {
            if (kk) { CONS_TAIL(bufB, ebB); } else { CONS_TAIL(bufA, ebA); }
        } else {
            if (kk) { CONS_FULL(bufB, ebB); } else { CONS_FULL(bufA, ebA); }
        }
    }

    // extract alpha[2*tl] and alpha[2*tl-1]  (log2 domain via p, el)
    int idx = 2 * tl;
    int lanehi = idx >> 2, rhi = idx & 3;
    int lanelo = (idx - 1) >> 2, rlo = (idx - 1) & 3;
    float q0 = __shfl(p0, lanehi, 64), q1 = __shfl(p1, lanehi, 64);
    float q2 = __shfl(p2, lanehi, 64), q3 = __shfl(p3, lanehi, 64);
    int   eh = __shfl(el, lanehi, 64);
    float ph = (rhi == 0) ? q0 : (rhi == 1) ? q1 : (rhi == 2) ? q2 : q3;
    float g0 = __shfl(p0, lanelo, 64), g1 = __shfl(p1, lanelo, 64);
    float g2 = __shfl(p2, lanelo, 64), g3 = __shfl(p3, lanelo, 64);
    int   eo = __shfl(el, lanelo, 64);
    float pl = (rlo == 0) ? g0 : (rlo == 1) ? g1 : (rlo == 2) ? g2 : g3;
    float vhi = (ph > 0.0f) ? __builtin_amdgcn_logf(ph) + (float)eh : -3.0e9f;
    float vlo = (pl > 0.0f) ? __builtin_amdgcn_logf(pl) + (float)eo : -3.0e9f;
    float m = fmaxf(vhi, vlo);
    float d = fminf(vhi, vlo) - m;
    float ll2 = m + __builtin_amdgcn_logf(1.0f + __builtin_amdgcn_exp2f(d));
    float nll = -ll2 * LN2;
    if (!(nll < 1e9f)) nll = 0.0f;      // zero_infinity (NaN-safe)

    int last = 0;
    if (l == 0) {
        nlls[b] = nll;
        __threadfence();
        unsigned old = __hip_atomic_fetch_add(cnt, 1u, __ATOMIC_ACQ_REL,
                                              __HIP_MEMORY_SCOPE_AGENT);
        last = (old == B_DIM - 1) ? 1 : 0;
    }
    last = __shfl(last, 0, 64);
    if (last) {
        float ps = 0.0f;
        for (int i = l; i < NB1; i += 64) ps += partials[i];
        for (int off = 32; off; off >>= 1) ps += __shfl_down(ps, off, 64);
        float cs = 0.0f;
        if (l < B_DIM) cs = nlls[l] / (float)tlen[l];
        for (int off = 32; off; off >>= 1) cs += __shfl_down(cs, off, 64);
        if (l == 0) {
            float smooth = -ps / (float)((long long)T_DIM * B_DIM * V_DIM);
            float ctc = cs / (float)B_DIM;
            out[0] = 0.9f * ctc + 0.1f * smooth;
        }
    }
}

extern "C" void kernel_launch(void* const* d_in, const int* in_sizes, int n_in,
                              void* d_out, int out_size, void* d_ws, size_t ws_size,
                              hipStream_t stream) {
    const float* lp  = (const float*)d_in[0];
    const int* tgt   = (const int*)d_in[1];
    const int* ilen  = (const int*)d_in[2];
    const int* tlen  = (const int*)d_in[3];
    float* out = (float*)d_out;
    float* ws  = (float*)d_ws;
    ctc_prep<<<NB1, 256, 0, stream>>>(lp, tgt, ws);
    ctc_rec<<<B_DIM, 128, 0, stream>>>(tgt, ilen, tlen, ws, out);
}

// Round 21
// 65.783 us; speedup vs baseline: 1.0178x; 1.0178x over previous
//
#include <hip/hip_runtime.h>
#include <hip/hip_bf16.h>

#define T_DIM 800
#define B_DIM 32
#define V_DIM 1024
#define S_DIM 100
#define L2E  1.4426950408889634f
#define LN2  0.6931471805599453f

#define NB1  1600                /* K1 blocks: 16 rows each */
#define EOFF 4096                /* E starts at ws + EOFF floats (16 KB) */
#define EROW 128                 /* padded E row: 104 used slots (512 B) */
#define BROWS 801                /* per-batch row stride (row 800 = overrun pad) */

// ws layout (32-bit slots):
// [0]                  : uint counter (zeroed by ctc_prep block 0 each call)
// [1 .. 1+NB1)         : float partial sums (smoothing reduction)
// [1+NB1 .. 1+NB1+32)  : float per-batch nll
// [EOFF ..)            : E[32][801][128] emission matrix (13.1 MB)

__device__ __forceinline__ float dpp_shr1_f(float x) {
    return __int_as_float(__builtin_amdgcn_update_dpp(
        0, __float_as_int(x), 0x138, 0xF, 0xF, false));
}
__device__ __forceinline__ int dpp_shr1_i(int x) {
    return __builtin_amdgcn_update_dpp(0, x, 0x138, 0xF, 0xF, false);
}
__device__ __forceinline__ float rl50(float x) {
    return __int_as_float(__builtin_amdgcn_readlane(__float_as_int(x), 50));
}
__device__ __forceinline__ void gl16(const float* g, float* lds_dst) {
    __builtin_amdgcn_global_load_lds(
        (const __attribute__((address_space(1))) unsigned int*)g,
        (__attribute__((address_space(3))) unsigned int*)lds_dst,
        16, 0, 0);
}

// ========== K1: fused smoothing-reduction + E build (R15-validated) ==========
extern "C" __global__ void __launch_bounds__(256)
ctc_prep(const float* __restrict__ lp,
         const int* __restrict__ tgt,
         float* __restrict__ ws)
{
    __shared__ float rb[4][2][V_DIM];   // 32 KB: per-wave double buffer
    __shared__ float red[4];
    float* E = ws + EOFF;
    float* partials = ws + 1;
    const int bid = blockIdx.x;
    const int tid = threadIdx.x;
    const int w = tid >> 6, j = tid & 63;
    const int b  = bid / 50;            // 50 blocks per batch
    const int t0 = (bid - b * 50) * 16 + w * 4;
    const int* tg = tgt + b * S_DIM;

    if (bid == 0 && tid == 0) ((unsigned int*)ws)[0] = 0;   // zero rec counter

    int c1 = 0, c2 = 0;
    if (j <= 49) { int2 t2 = ((const int2*)tg)[j]; c1 = t2.x; c2 = t2.y; }

    float s = 0.0f;
    #pragma unroll
    for (int i = 0; i < 4; ++i) {
        const int t = t0 + i;
        const float4* src = (const float4*)(lp + ((size_t)t * B_DIM + b) * V_DIM);
        float4 va = src[j], vb = src[j + 64], vc = src[j + 128], vd = src[j + 192];
        s += ((va.x + va.y) + (va.z + va.w)) + ((vb.x + vb.y) + (vb.z + vb.w))
           + ((vc.x + vc.y) + (vc.z + vc.w)) + ((vd.x + vd.y) + (vd.z + vd.w));
        float* rw = rb[w][i & 1];
        ((float4*)rw)[j] = va; ((float4*)rw)[j + 64] = vb;
        ((float4*)rw)[j + 128] = vc; ((float4*)rw)[j + 192] = vd;
        float a, c;
        if (j <= 49)      { a = __builtin_amdgcn_exp2f(rw[c1] * L2E);
                            c = __builtin_amdgcn_exp2f(rw[c2] * L2E); }
        else if (j == 50) { float ebv = __builtin_amdgcn_exp2f(rw[0] * L2E);
                            a = ebv; c = ebv; }
        else              { a = 0.0f; c = 0.0f; }
        ((float2*)(E + ((size_t)b * BROWS + t) * EROW))[j] = make_float2(a, c);
    }
    for (int off = 32; off; off >>= 1) s += __shfl_down(s, off, 64);
    if (j == 0) red[w] = s;
    __syncthreads();
    if (tid == 0) partials[bid] = (red[0] + red[1]) + (red[2] + red[3]);
}

// ========== K2: recursion — producer/consumer wave split (R16-validated) ==========
extern "C" __global__ void __launch_bounds__(128)
ctc_rec(const int* __restrict__ tgt,
        const int* __restrict__ ilen,
        const int* __restrict__ tlen,
        float* __restrict__ ws,
        float* __restrict__ out)
{
    __shared__ float bufA[32 * EROW];   // 16 KB
    __shared__ float bufB[32 * EROW];   // 16 KB
    unsigned int* cnt = (unsigned int*)ws;
    float* partials = ws + 1;
    float* nlls = ws + 1 + NB1;
    const int b = blockIdx.x;
    const int tid = threadIdx.x;
    const int wav = tid >> 6;
    const int l = tid & 63;
    const float* E = ws + EOFF + (size_t)b * BROWS * EROW;
    const int* tg = tgt + b * S_DIM;
    const int len = ilen[b];
    const int tl  = tlen[b];
    const int steps = len - 1;          // t = 1..len-1 ; len in [400,800]
    const int nfull = steps >> 5;
    const int nst   = steps & 31;
    const int N     = nfull + (nst ? 1 : 0);

#define STAGE_P(BUFP, SB) do { \
    const int tb_ = 1 + 32 * (SB); \
    float* bp_ = (BUFP); \
    _Pragma("unroll") \
    for (int g_ = 0; g_ < 16; ++g_) { \
        gl16(E + (size_t)(tb_ + 2 * g_) * EROW + 4 * l, bp_ + g_ * 256); \
    } \
} while (0)

#define WAIT0 do { \
    asm volatile("s_waitcnt vmcnt(0)" ::: "memory"); \
    __builtin_amdgcn_sched_barrier(0); \
} while (0)

    if (wav == 1) {
        // ---------------- stager wave ----------------
        STAGE_P(bufA, 0); WAIT0;
        __builtin_amdgcn_s_barrier();                // bar#0: buf(0) ready
        #pragma unroll 1
        for (int k = 1; k < N; ++k) {
            STAGE_P((k & 1) ? bufB : bufA, k); WAIT0;
            __builtin_amdgcn_s_barrier();            // bar#k
        }
        return;                                       // exactly N barriers
    }

    // ---------------- consumer wave ----------------
    float cs1f = 0, cs3f = 0;
    if (l <= 49) {
        int v1 = tg[2 * l];
        int vp = (l >= 1) ? tg[2 * l - 1] : -1;
        cs1f = (v1 != vp) ? 1.0f : 0.0f;
        int v3 = tg[2 * l + 1];
        cs3f = (v3 != v1) ? 1.0f : 0.0f;
    }

    float p0 = 0, p1 = 0, p2 = 0, p3 = 0;
    float qv = 0, sff = 0, sfg = 0;
    int   el = 0, eLp = 0;
    {
        float2 q0 = ((const float2*)E)[l];
        float eb0 = rl50(q0.x);
        p0 = (l == 0) ? eb0  : 0.0f;
        p1 = (l == 0) ? q0.x : 0.0f;
    }

    float2 ga0, ga1, ga2, ga3, gb0, gb1, gb2, gb3;

#define PREF_(BUF, G, R0, R1, R2, R3) do { \
    const float2* bp_ = (const float2*)(BUF); \
    R0 = bp_[(4 * (G) + 0) * 64 + l]; \
    R1 = bp_[(4 * (G) + 1) * 64 + l]; \
    R2 = bp_[(4 * (G) + 2) * 64 + l]; \
    R3 = bp_[(4 * (G) + 3) * 64 + l]; \
} while (0)

#define BD do { \
    float mz_ = fmaxf(fmaxf(p0, p1), fmaxf(p2, p3)); \
    int dead_ = (mz_ == 0.0f) ? 1 : 0; \
    int er_ = (int)((__float_as_uint(mz_) >> 23) & 255u); \
    unsigned fld_ = dead_ ? 127u : (unsigned)(254 - er_); \
    float sc_ = __uint_as_float(fld_ << 23); \
    p0 *= sc_; p1 *= sc_; p2 *= sc_; p3 *= sc_; \
    el += dead_ ? 0 : (er_ - 127); \
    int e1s_ = dpp_shr1_i(el); \
    int elA_ = dead_ ? e1s_ : el; \
    int e2s_ = dpp_shr1_i(elA_); \
    int elB_ = dead_ ? e2s_ : el; \
    int e3s_ = dpp_shr1_i(elB_); \
    int d1_ = e3s_ - elB_; d1_ = d1_ < -120 ? -120 : (d1_ > 120 ? 120 : d1_); \
    int d2_ = eLp  - elB_; d2_ = d2_ < -120 ? -120 : (d2_ > 120 ? 120 : d2_); \
    sfg = (l == 0) ? 0.0f : __uint_as_float((unsigned)(d1_ + 127) << 23); \
    sff = (l == 0) ? 0.0f : __uint_as_float((unsigned)(d2_ + 127) << 23); \
    el = elB_; eLp = e3s_; \
} while (0)

#define ST(SF, Q, EBS) do { \
    float h3_ = qv * (SF); \
    float vown_ = fmaf(cs3f, p1, p2 + p3); \
    float n3_ = vown_ * (Q).y; \
    float n0_ = (p0 + h3_) * (EBS); \
    float n1_ = fmaf(cs1f, h3_, p0 + p1) * (Q).x; \
    float n2_ = (p1 + p2) * (EBS); \
    qv = dpp_shr1_f(n3_); \
    p0 = n0_; p1 = n1_; p2 = n2_; p3 = n3_; \
} while (0)

#define GRP_(R0, R1, R2, R3) do { \
    BD; \
    ST(sff, R0, rl50(R0.x)); \
    ST(sfg, R1, rl50(R1.x)); \
    ST(sfg, R2, rl50(R2.x)); \
    ST(sfg, R3, rl50(R3.x)); \
} while (0)

#define GRPT_(R0, R1, R2, R3, BASE) do { \
    if ((BASE) < nst) { \
        BD; \
        ST(sff, R0, rl50(R0.x)); \
        if ((BASE) + 1 < nst) ST(sfg, R1, rl50(R1.x)); \
        if ((BASE) + 2 < nst) ST(sfg, R2, rl50(R2.x)); \
        if ((BASE) + 3 < nst) ST(sfg, R3, rl50(R3.x)); \
    } \
} while (0)

#define CONS_FULL(BUF) do { \
    PREF_(BUF, 0, ga0, ga1, ga2, ga3); \
    PREF_(BUF, 1, gb0, gb1, gb2, gb3); GRP_(ga0, ga1, ga2, ga3); \
    PREF_(BUF, 2, ga0, ga1, ga2, ga3); GRP_(gb0, gb1, gb2, gb3); \
    PREF_(BUF, 3, gb0, gb1, gb2, gb3); GRP_(ga0, ga1, ga2, ga3); \
    PREF_(BUF, 4, ga0, ga1, ga2, ga3); GRP_(gb0, gb1, gb2, gb3); \
    PREF_(BUF, 5, gb0, gb1, gb2, gb3); GRP_(ga0, ga1, ga2, ga3); \
    PREF_(BUF, 6, ga0, ga1, ga2, ga3); GRP_(gb0, gb1, gb2, gb3); \
    PREF_(BUF, 7, gb0, gb1, gb2, gb3); GRP_(ga0, ga1, ga2, ga3); \
    GRP_(gb0, gb1, gb2, gb3); \
} while (0)

#define CONS_TAIL(BUF) do { \
    PREF_(BUF, 0, ga0, ga1, ga2, ga3); \
    PREF_(BUF, 1, gb0, gb1, gb2, gb3); GRPT_(ga0, ga1, ga2, ga3, 0); \
    PREF_(BUF, 2, ga0, ga1, ga2, ga3); GRPT_(gb0, gb1, gb2, gb3, 4); \
    PREF_(BUF, 3, gb0, gb1, gb2, gb3); GRPT_(ga0, ga1, ga2, ga3, 8); \
    PREF_(BUF, 4, ga0, ga1, ga2, ga3); GRPT_(gb0, gb1, gb2, gb3, 12); \
    PREF_(BUF, 5, gb0, gb1, gb2, gb3); GRPT_(ga0, ga1, ga2, ga3, 16); \
    PREF_(BUF, 6, ga0, ga1, ga2, ga3); GRPT_(gb0, gb1, gb2, gb3, 20); \
    PREF_(BUF, 7, gb0, gb1, gb2, gb3); GRPT_(ga0, ga1, ga2, ga3, 24); \
    GRPT_(gb0, gb1, gb2, gb3, 28); \
} while (0)

    __builtin_amdgcn_s_barrier();                    // bar#0: buf(0) ready
    #pragma unroll 1
    for (int k = 0; k + 1 < N; ++k) {
        const float* cur = (k & 1) ? bufB : bufA;
        CONS_FULL(cur);
        __builtin_amdgcn_s_barrier();                // bar#k+1
    }
    {
        const float* cur = ((N - 1) & 1) ? bufB : bufA;
        if (nst) { CONS_TAIL(cur); } else { CONS_FULL(cur); }
    }

    // extract alpha[2*tl] and alpha[2*tl-1]  (log2 domain via p, el)
    int idx = 2 * tl;
    int lanehi = idx >> 2, rhi = idx & 3;
    int lanelo = (idx - 1) >> 2, rlo = (idx - 1) & 3;
    float q0 = __shfl(p0, lanehi, 64), q1 = __shfl(p1, lanehi, 64);
    float q2 = __shfl(p2, lanehi, 64), q3 = __shfl(p3, lanehi, 64);
    int   eh = __shfl(el, lanehi, 64);
    float ph = (rhi == 0) ? q0 : (rhi == 1) ? q1 : (rhi == 2) ? q2 : q3;
    float g0 = __shfl(p0, lanelo, 64), g1 = __shfl(p1, lanelo, 64);
    float g2 = __shfl(p2, lanelo, 64), g3 = __shfl(p3, lanelo, 64);
    int   eo = __shfl(el, lanelo, 64);
    float pl = (rlo == 0) ? g0 : (rlo == 1) ? g1 : (rlo == 2) ? g2 : g3;
    float vhi = (ph > 0.0f) ? __builtin_amdgcn_logf(ph) + (float)eh : -3.0e9f;
    float vlo = (pl > 0.0f) ? __builtin_amdgcn_logf(pl) + (float)eo : -3.0e9f;
    float m = fmaxf(vhi, vlo);
    float d = fminf(vhi, vlo) - m;
    float ll2 = m + __builtin_amdgcn_logf(1.0f + __builtin_amdgcn_exp2f(d));
    float nll = -ll2 * LN2;
    if (!(nll < 1e9f)) nll = 0.0f;      // zero_infinity (NaN-safe)

    int last = 0;
    if (l == 0) {
        nlls[b] = nll;
        __threadfence();
        unsigned old = __hip_atomic_fetch_add(cnt, 1u, __ATOMIC_ACQ_REL,
                                              __HIP_MEMORY_SCOPE_AGENT);
        last = (old == B_DIM - 1) ? 1 : 0;
    }
    last = __shfl(last, 0, 64);
    if (last) {
        float ps = 0.0f;
        for (int i = l; i < NB1; i += 64) ps += partials[i];
        for (int off = 32; off; off >>= 1) ps += __shfl_down(ps, off, 64);
        float cs = 0.0f;
        if (l < B_DIM) cs = nlls[l] / (float)tlen[l];
        for (int off = 32; off; off >>= 1) cs += __shfl_down(cs, off, 64);
        if (l == 0) {
            float smooth = -ps / (float)((long long)T_DIM * B_DIM * V_DIM);
            float ctc = cs / (float)B_DIM;
            out[0] = 0.9f * ctc + 0.1f * smooth;
        }
    }
}

extern "C" void kernel_launch(void* const* d_in, const int* in_sizes, int n_in,
                              void* d_out, int out_size, void* d_ws, size_t ws_size,
                              hipStream_t stream) {
    const float* lp  = (const float*)d_in[0];
    const int* tgt   = (const int*)d_in[1];
    const int* ilen  = (const int*)d_in[2];
    const int* tlen  = (const int*)d_in[3];
    float* out = (float*)d_out;
    float* ws  = (float*)d_ws;
    ctc_prep<<<NB1, 256, 0, stream>>>(lp, tgt, ws);
    ctc_rec<<<B_DIM, 128, 0, stream>>>(tgt, ilen, tlen, ws, out);
}